// Round 4
// baseline (116.539 us; speedup 1.0000x reference)
//
#include <hip/hip_runtime.h>
#include <hip/hip_bf16.h>
#include <stdint.h>

#define IN_F  4096
#define OUT_F 11008
#define MTOT  512

#define BM 128
#define BN 128
#define BK 64
#define NKT (IN_F / BK)            // 64 K-tiles
#define A_TILE_B (BM * BK * 2)     // 16384 B
#define B_TILE_B (BN * BK * 2)     // 16384 B
#define X_WS_BYTES ((size_t)MTOT * IN_F * 2)   // 4 MiB

typedef __attribute__((ext_vector_type(4))) float  f32x4;
typedef __attribute__((ext_vector_type(4))) int    i32x4;
typedef __attribute__((ext_vector_type(2))) unsigned u32x2;
typedef __attribute__((ext_vector_type(4))) unsigned u32x4;
typedef __attribute__((ext_vector_type(8))) __bf16 bf16x8;

// f32 -> bf16 pair, round-to-nearest (for X)
__device__ __forceinline__ unsigned pack2bf16_rnd(float lo, float hi) {
    unsigned ulo = __builtin_bit_cast(unsigned, lo) + 0x8000u;
    unsigned uhi = __builtin_bit_cast(unsigned, hi) + 0x8000u;
    return __builtin_amdgcn_perm(uhi, ulo, 0x07060302u);
}
// f32 -> bf16 pair, truncation (exact for ints |q|<=127)
__device__ __forceinline__ unsigned pack2bf16_exact(float lo, float hi) {
    return __builtin_amdgcn_perm(__builtin_bit_cast(unsigned, hi),
                                 __builtin_bit_cast(unsigned, lo), 0x07060302u);
}

__device__ __forceinline__ void gload_lds16(const void* g, void* l) {
    __builtin_amdgcn_global_load_lds(
        (const __attribute__((address_space(1))) unsigned*)g,
        (__attribute__((address_space(3))) unsigned*)l, 16, 0, 0);
}

// ---- Prepass: X fp32 -> bf16, stored as [mtile][kt][swizzled 16KB tile] ----
// Within a tile, element (row_l, k_l) lives at byte p = a ^ ((row_l&7)<<4),
// a = row_l*128 + k_l*2.  (Involution; matches the main kernel's frag reads.)
__global__ __launch_bounds__(256)
void xconv_kernel(const float* __restrict__ X, char* __restrict__ xws) {
    const int gid  = blockIdx.x * 256 + threadIdx.x;   // 262144 threads
    const int row  = gid >> 9;          // 512 8-elem chunks per row
    const int col0 = (gid & 511) * 8;
    const float* src = X + (size_t)row * IN_F + col0;
    f32x4 v0 = *(const f32x4*)(src);
    f32x4 v1 = *(const f32x4*)(src + 4);
    u32x4 o;
    o.x = pack2bf16_rnd(v0.x, v0.y);
    o.y = pack2bf16_rnd(v0.z, v0.w);
    o.z = pack2bf16_rnd(v1.x, v1.y);
    o.w = pack2bf16_rnd(v1.z, v1.w);
    const int mtile = row >> 7, row_l = row & 127;
    const int kt = col0 >> 6,  k_l  = col0 & 63;
    const int a = row_l * 128 + k_l * 2;
    const int p = a ^ ((row_l & 7) << 4);
    *(u32x4*)(xws + (size_t)mtile * (NKT * A_TILE_B)
                  + (size_t)kt * A_TILE_B + p) = o;
}

// ---- Main GEMM: 128x128 tile, 8 waves, A via global_load_lds (dbuf), B reg-staged ----
template<bool USE_WS>
__global__ __launch_bounds__(512, 4)
void qgemm_kernel(const float* __restrict__ X, const char* __restrict__ xws,
                  const int*   __restrict__ W,
                  const float* __restrict__ scale,
                  const float* __restrict__ bias,
                  float* __restrict__ Out)
{
    __shared__ __align__(16) char smem[2 * A_TILE_B + B_TILE_B];  // 48 KiB
    char* bufA0 = smem;
    char* bufA1 = smem + A_TILE_B;
    char* bufB  = smem + 2 * A_TILE_B;

    const int tid  = (int)threadIdx.x;
    const int lane = tid & 63;
    const int wid  = tid >> 6;     // 0..7
    const int wr   = wid >> 2;     // 0..1 -> 64 output rows
    const int wc   = wid & 3;      // 0..3 -> 32 output cols

    // mtile-major XCD mapping: 344 = 8*43 exact. XCD x gets g in [x*43,(x+1)*43)
    // -> one mtile per XCD (X panel 1 MB bf16, L2-resident); W streamed once/mtile.
    const int bid = (int)blockIdx.x;
    const int g = (bid & 7) * 43 + (bid >> 3);
    const int mtile = g / 86;
    const int ntile = g % 86;
    const int brow = mtile * BM;
    const int bcol = ntile * BN;

    // B staging map: 128 rows x 16 chunks / 512 thr = 4 chunks per thread
    const int srow  = tid >> 4;    // 0..31
    const int scol4 = tid & 15;
    const int* Wp = W + (size_t)(bcol + srow) * IN_F + scol4 * 4;
    const float* Xp = X + (size_t)(brow + srow) * IN_F + scol4 * 4;  // fallback

    const char* xsrc = xws + (size_t)mtile * (NKT * A_TILE_B)
                     + wid * 1024 + lane * 16;

    i32x4 rb[4];
    f32x4 acc[4][2];
    #pragma unroll
    for (int i = 0; i < 4; ++i)
        #pragma unroll
        for (int j = 0; j < 2; ++j)
            acc[i][j] = (f32x4){0.f, 0.f, 0.f, 0.f};

    // prologue: B regs for kt=0; A(0) -> bufA0
    #pragma unroll
    for (int j = 0; j < 4; ++j)
        rb[j] = *(const i32x4*)(Wp + (size_t)(j * 32) * IN_F);
    if constexpr (USE_WS) {
        gload_lds16(xsrc, bufA0 + wid * 1024);
        gload_lds16(xsrc + 8192, bufA0 + wid * 1024 + 8192);
    }

    for (int kt = 0; kt < NKT; ++kt) {
        char* curA = USE_WS ? ((kt & 1) ? bufA1 : bufA0) : bufA0;

        // --- stage B(kt) from regs (and A(kt) in fallback) ---
        #pragma unroll
        for (int j = 0; j < 4; ++j) {
            const int row = j * 32 + srow;
            const int off = (row * 128 + scol4 * 8) ^ ((row & 7) << 4);
            u32x2 bv;
            bv.x = pack2bf16_exact((float)rb[j].x, (float)rb[j].y);
            bv.y = pack2bf16_exact((float)rb[j].z, (float)rb[j].w);
            *(u32x2*)(bufB + off) = bv;
        }
        if constexpr (!USE_WS) {
            #pragma unroll
            for (int j = 0; j < 4; ++j) {
                f32x4 ra = *(const f32x4*)(Xp + (size_t)kt * BK
                                              + (size_t)(j * 32) * IN_F);
                const int row = j * 32 + srow;
                const int off = (row * 128 + scol4 * 8) ^ ((row & 7) << 4);
                u32x2 av;
                av.x = pack2bf16_rnd(ra.x, ra.y);
                av.y = pack2bf16_rnd(ra.z, ra.w);
                *(u32x2*)(bufA0 + off) = av;
            }
        }
        __syncthreads();   // drains A(kt) gload (issued last iter) + B writes

        // --- issue next-tile loads; they drain at the NEXT barrier, covered
        //     by the MFMA phase below ---
        if (kt + 1 < NKT) {
            if constexpr (USE_WS) {
                char* nxtA = (kt & 1) ? bufA0 : bufA1;
                const char* xs = xsrc + (size_t)(kt + 1) * A_TILE_B;
                gload_lds16(xs, nxtA + wid * 1024);
                gload_lds16(xs + 8192, nxtA + wid * 1024 + 8192);
            }
            const int* Wk = Wp + (size_t)(kt + 1) * BK;
            #pragma unroll
            for (int j = 0; j < 4; ++j)
                rb[j] = *(const i32x4*)(Wk + (size_t)(j * 32) * IN_F);
        }

        // --- compute: 2 K-steps, per wave 4x2 fragments = 16 MFMA ---
        #pragma unroll
        for (int ks = 0; ks < 2; ++ks) {
            bf16x8 af[4], bfr[2];
            #pragma unroll
            for (int mi = 0; mi < 4; ++mi) {
                const int row = wr * 64 + mi * 16 + (lane & 15);
                const int off = (row * 128 + ks * 64 + (lane >> 4) * 16)
                                ^ ((row & 7) << 4);
                af[mi] = *(const bf16x8*)(curA + off);
            }
            #pragma unroll
            for (int ni = 0; ni < 2; ++ni) {
                const int row = wc * 32 + ni * 16 + (lane & 15);
                const int off = (row * 128 + ks * 64 + (lane >> 4) * 16)
                                ^ ((row & 7) << 4);
                bfr[ni] = *(const bf16x8*)(bufB + off);
            }
            #pragma unroll
            for (int mi = 0; mi < 4; ++mi)
                #pragma unroll
                for (int ni = 0; ni < 2; ++ni)
                    acc[mi][ni] = __builtin_amdgcn_mfma_f32_16x16x32_bf16(
                        af[mi], bfr[ni], acc[mi][ni], 0, 0, 0);
        }
        __syncthreads();   // drains next-tile gload/loads; LDS reads done
    }

    // --- epilogue: out = acc / scale[col] + bias[col] ---
    // C/D mapping: col = lane&15, row = (lane>>4)*4 + j
    #pragma unroll
    for (int ni = 0; ni < 2; ++ni) {
        const int col = bcol + wc * 32 + ni * 16 + (lane & 15);
        const float inv = 1.0f / scale[col];
        const float bs  = bias[col];
        #pragma unroll
        for (int mi = 0; mi < 4; ++mi) {
            const int row0 = brow + wr * 64 + mi * 16 + ((lane >> 4) << 2);
            #pragma unroll
            for (int j = 0; j < 4; ++j) {
                Out[(size_t)(row0 + j) * OUT_F + col] = acc[mi][ni][j] * inv + bs;
            }
        }
    }
}

extern "C" void kernel_launch(void* const* d_in, const int* in_sizes, int n_in,
                              void* d_out, int out_size, void* d_ws, size_t ws_size,
                              hipStream_t stream) {
    const float* X     = (const float*)d_in[0];
    const int*   W     = (const int*)d_in[1];
    const float* scale = (const float*)d_in[2];
    const float* bias  = (const float*)d_in[3];
    float* Out = (float*)d_out;

    const int grid = (MTOT / BM) * (OUT_F / BN);  // 4 * 86 = 344

    if (ws_size >= X_WS_BYTES) {
        char* xws = (char*)d_ws;
        xconv_kernel<<<(MTOT * IN_F / 8) / 256, 256, 0, stream>>>(X, xws);
        qgemm_kernel<true><<<grid, 512, 0, stream>>>(X, xws, W, scale, bias, Out);
    } else {
        qgemm_kernel<false><<<grid, 512, 0, stream>>>(X, nullptr, W, scale, bias, Out);
    }
}

// Round 5
// 91.998 us; speedup vs baseline: 1.2668x; 1.2668x over previous
//
#include <hip/hip_runtime.h>
#include <hip/hip_bf16.h>
#include <stdint.h>

#define IN_F  4096
#define OUT_F 11008
#define MTOT  512

#define BM 128
#define BN 64
#define BK 64
#define NKT (IN_F / BK)            // 64 K-tiles
#define A_TILE_B (BM * BK * 2)     // 16384 B
#define B_TILE_B (BN * BK * 2)     // 8192 B
#define X_WS_BYTES ((size_t)MTOT * IN_F * 2)   // 4 MiB

typedef __attribute__((ext_vector_type(4))) float  f32x4;
typedef __attribute__((ext_vector_type(4))) int    i32x4;
typedef __attribute__((ext_vector_type(2))) unsigned u32x2;
typedef __attribute__((ext_vector_type(4))) unsigned u32x4;
typedef __attribute__((ext_vector_type(8))) __bf16 bf16x8;

// f32 -> bf16 pair, round-to-nearest (for X)
__device__ __forceinline__ unsigned pack2bf16_rnd(float lo, float hi) {
    unsigned ulo = __builtin_bit_cast(unsigned, lo) + 0x8000u;
    unsigned uhi = __builtin_bit_cast(unsigned, hi) + 0x8000u;
    return __builtin_amdgcn_perm(uhi, ulo, 0x07060302u);
}
// f32 -> bf16 pair, truncation (exact for ints |q|<=127)
__device__ __forceinline__ unsigned pack2bf16_exact(float lo, float hi) {
    return __builtin_amdgcn_perm(__builtin_bit_cast(unsigned, hi),
                                 __builtin_bit_cast(unsigned, lo), 0x07060302u);
}

__device__ __forceinline__ void gload_lds16(const void* g, void* l) {
    __builtin_amdgcn_global_load_lds(
        (const __attribute__((address_space(1))) unsigned*)g,
        (__attribute__((address_space(3))) unsigned*)l, 16, 0, 0);
}

// ---- Prepass: X fp32 -> bf16, stored as [mtile][kt][swizzled 16KB tile] ----
// Element (row_l, k_l) of a tile lives at byte p = a ^ ((row_l&7)<<4),
// a = row_l*128 + k_l*2 (involution; matches the GEMM's fragment reads).
__global__ __launch_bounds__(256)
void xconv_kernel(const float* __restrict__ X, char* __restrict__ xws) {
    const int gid  = blockIdx.x * 256 + threadIdx.x;   // 262144 threads
    const int row  = gid >> 9;          // 512 8-elem chunks per row
    const int col0 = (gid & 511) * 8;
    const float* src = X + (size_t)row * IN_F + col0;
    f32x4 v0 = *(const f32x4*)(src);
    f32x4 v1 = *(const f32x4*)(src + 4);
    u32x4 o;
    o.x = pack2bf16_rnd(v0.x, v0.y);
    o.y = pack2bf16_rnd(v0.z, v0.w);
    o.z = pack2bf16_rnd(v1.x, v1.y);
    o.w = pack2bf16_rnd(v1.z, v1.w);
    const int mtile = row >> 7, row_l = row & 127;
    const int kt = col0 >> 6,  k_l  = col0 & 63;
    const int a = row_l * 128 + k_l * 2;
    const int p = a ^ ((row_l & 7) << 4);
    *(u32x4*)(xws + (size_t)mtile * (NKT * A_TILE_B)
                  + (size_t)kt * A_TILE_B + p) = o;
}

// ---- Main GEMM: BM=128 x BN=64, 2 waves, wave tile 64x64 (32 FLOP/LDS-byte).
//      A via global_load_lds from xws (double-buffered), B reg-staged+converted.
template<bool USE_WS>
__global__ __launch_bounds__(128, 2)
void qgemm_kernel(const float* __restrict__ X, const char* __restrict__ xws,
                  const int*   __restrict__ W,
                  const float* __restrict__ scale,
                  const float* __restrict__ bias,
                  float* __restrict__ Out)
{
    __shared__ __align__(16) char smem[2 * A_TILE_B + B_TILE_B];  // 40 KiB
    char* bufA0 = smem;
    char* bufA1 = smem + A_TILE_B;
    char* bufB  = smem + 2 * A_TILE_B;

    const int tid  = (int)threadIdx.x;
    const int lane = tid & 63;
    const int w    = tid >> 6;     // wave 0..1 -> rows [w*64, w*64+64)

    // XCD mapping (R2/R3-proven): consecutive local ids within an XCD are the
    // 4 mtiles of one ntile, then the next ntile -> W panel L2-shared 4-way,
    // W stays L3-resident across replays. grid = 688 = 8*86 exact.
    const int bid  = (int)blockIdx.x;
    const int lbid = (bid & 7) * 86 + (bid >> 3);
    const int mtile = lbid & 3;        // M/BM = 4
    const int ntile = lbid >> 2;       // N/BN = 172
    const int brow = mtile * BM;
    const int bcol = ntile * BN;

    // B staging: thread t covers rows (t>>4)+k*8 (k=0..7), i32x4 chunk t&15.
    const int srow  = tid >> 4;    // 0..7
    const int scol4 = tid & 15;    // 0..15
    const int* Wp = W + (size_t)(bcol + srow) * IN_F + scol4 * 4;
    const float* Xp = X + (size_t)(brow + srow) * IN_F + scol4 * 4;  // fallback

    const char* xsrc = xws + (size_t)mtile * (NKT * A_TILE_B)
                     + w * 8192 + lane * 16;

    i32x4 rb[8];
    f32x4 acc[4][4];
    #pragma unroll
    for (int i = 0; i < 4; ++i)
        #pragma unroll
        for (int j = 0; j < 4; ++j)
            acc[i][j] = (f32x4){0.f, 0.f, 0.f, 0.f};

    // prologue: B(0) -> regs; A(0) -> bufA0 via DMA
    #pragma unroll
    for (int k = 0; k < 8; ++k)
        rb[k] = *(const i32x4*)(Wp + (size_t)(k * 8) * IN_F);
    if constexpr (USE_WS) {
        #pragma unroll
        for (int c = 0; c < 8; ++c)
            gload_lds16(xsrc + c * 1024, bufA0 + w * 8192 + c * 1024);
    }

    for (int kt = 0; kt < NKT; ++kt) {
        char* curA = USE_WS ? ((kt & 1) ? bufA1 : bufA0) : bufA0;

        // --- phase 1: stage B(kt) from regs (convert int32 -> bf16) ---
        #pragma unroll
        for (int k = 0; k < 8; ++k) {
            const int row = srow + k * 8;
            const int off = (row * 128 + scol4 * 8) ^ ((row & 7) << 4);
            u32x2 bv;
            bv.x = pack2bf16_exact((float)rb[k].x, (float)rb[k].y);
            bv.y = pack2bf16_exact((float)rb[k].z, (float)rb[k].w);
            *(u32x2*)(bufB + off) = bv;
        }
        if constexpr (!USE_WS) {
            // fallback only (ws too small): stage A from X with convert
            #pragma unroll
            for (int k = 0; k < 16; ++k) {
                f32x4 ra = *(const f32x4*)(Xp + (size_t)kt * BK
                                              + (size_t)(k * 8) * IN_F);
                const int row = srow + k * 8;
                const int off = (row * 128 + scol4 * 8) ^ ((row & 7) << 4);
                u32x2 av;
                av.x = pack2bf16_rnd(ra.x, ra.y);
                av.y = pack2bf16_rnd(ra.z, ra.w);
                *(u32x2*)(bufA0 + off) = av;
            }
        }
        __syncthreads();   // drains A(kt) DMA (issued last iter) + B writes

        // --- phase 2: issue next-tile loads first (max cover), then MFMA ---
        if (kt + 1 < NKT) {
            if constexpr (USE_WS) {
                char* nxtA = (kt & 1) ? bufA0 : bufA1;
                const char* xs = xsrc + (size_t)(kt + 1) * A_TILE_B;
                #pragma unroll
                for (int c = 0; c < 8; ++c)
                    gload_lds16(xs + c * 1024, nxtA + w * 8192 + c * 1024);
            }
            const int* Wk = Wp + (size_t)(kt + 1) * BK;
            #pragma unroll
            for (int k = 0; k < 8; ++k)
                rb[k] = *(const i32x4*)(Wk + (size_t)(k * 8) * IN_F);
        }

        // wave tile 64x64: 4 A-frags x 4 B-frags x 2 K-steps = 32 MFMA
        #pragma unroll
        for (int ks = 0; ks < 2; ++ks) {
            bf16x8 af[4], bfr[4];
            #pragma unroll
            for (int mi = 0; mi < 4; ++mi) {
                const int row = w * 64 + mi * 16 + (lane & 15);
                const int off = (row * 128 + ks * 64 + (lane >> 4) * 16)
                                ^ ((row & 7) << 4);
                af[mi] = *(const bf16x8*)(curA + off);
            }
            #pragma unroll
            for (int ni = 0; ni < 4; ++ni) {
                const int row = ni * 16 + (lane & 15);
                const int off = (row * 128 + ks * 64 + (lane >> 4) * 16)
                                ^ ((row & 7) << 4);
                bfr[ni] = *(const bf16x8*)(bufB + off);
            }
            #pragma unroll
            for (int mi = 0; mi < 4; ++mi)
                #pragma unroll
                for (int ni = 0; ni < 4; ++ni)
                    acc[mi][ni] = __builtin_amdgcn_mfma_f32_16x16x32_bf16(
                        af[mi], bfr[ni], acc[mi][ni], 0, 0, 0);
        }
        __syncthreads();   // next-tile DMA/loads drain here (covered by MFMA)
    }

    // --- epilogue: out = acc / scale[col] + bias[col] ---
    // C/D mapping: col = lane&15, row = (lane>>4)*4 + j
    #pragma unroll
    for (int ni = 0; ni < 4; ++ni) {
        const int col = bcol + ni * 16 + (lane & 15);
        const float inv = 1.0f / scale[col];
        const float bs  = bias[col];
        #pragma unroll
        for (int mi = 0; mi < 4; ++mi) {
            const int row0 = brow + w * 64 + mi * 16 + ((lane >> 4) << 2);
            #pragma unroll
            for (int j = 0; j < 4; ++j) {
                Out[(size_t)(row0 + j) * OUT_F + col] = acc[mi][ni][j] * inv + bs;
            }
        }
    }
}

extern "C" void kernel_launch(void* const* d_in, const int* in_sizes, int n_in,
                              void* d_out, int out_size, void* d_ws, size_t ws_size,
                              hipStream_t stream) {
    const float* X     = (const float*)d_in[0];
    const int*   W     = (const int*)d_in[1];
    const float* scale = (const float*)d_in[2];
    const float* bias  = (const float*)d_in[3];
    float* Out = (float*)d_out;

    const int grid = (MTOT / BM) * (OUT_F / BN);  // 4 * 172 = 688

    if (ws_size >= X_WS_BYTES) {
        char* xws = (char*)d_ws;
        xconv_kernel<<<(MTOT * IN_F / 8) / 256, 256, 0, stream>>>(X, xws);
        qgemm_kernel<true><<<grid, 128, 0, stream>>>(X, xws, W, scale, bias, Out);
    } else {
        qgemm_kernel<false><<<grid, 128, 0, stream>>>(X, nullptr, W, scale, bias, Out);
    }
}